// Round 1
// baseline (62.691 us; speedup 1.0000x reference)
//
#include <hip/hip_runtime.h>

// Problem constants (from reference setup_inputs)
constexpr int Bn  = 8;
constexpr int Hn  = 512;
constexpr int Wn  = 512;
constexpr int HWn = Hn * Wn;          // 262144
constexpr int NPIX = Bn * HWn;        // 2097152

// conn offsets (dy,dx) in channel order:
// [down_right, down, down_left, right, left, up_right, up, up_left]
// conn_t[i][r,c] = t[r,c] * t[r-dy, c-dx]
// vote[i][r,c]   = p_i[r,c] * p_{7-i}[r-dy, c-dx]   (same neighbor location)
__constant__ int c_dy[8] = {1, 1, 1, 0, 0, -1, -1, -1};
__constant__ int c_dx[8] = {1, 0, -1, 1, -1, 1, 0, -1};

__global__ __launch_bounds__(256) void connect_loss_main(
    const float* __restrict__ cm,   // (B,8,H,W)
    const int*   __restrict__ tg,   // (B,1,H,W)
    float*       __restrict__ ws)   // 6 accumulators
{
    float s_conn = 0.f, s_bimap = 0.f, s_edge = 0.f;
    float s_inter = 0.f, s_fp = 0.f, s_t = 0.f;

    const int stride = gridDim.x * blockDim.x;
    for (int idx = blockIdx.x * blockDim.x + threadIdx.x; idx < NPIX; idx += stride) {
        const int c = idx & (Wn - 1);
        const int r = (idx >> 9) & (Hn - 1);
        const int b = idx >> 18;
        const float* cmb = cm + (size_t)b * 8 * HWn;
        const int*   tgb = tg + (size_t)b * HWn;

        const float t_own = (float)tgb[r * Wn + c];

        // own logits -> p, log p (log(1-p) = log p - x)
        float x[8], p[8], lp[8];
        #pragma unroll
        for (int i = 0; i < 8; ++i) {
            x[i] = cmb[i * HWn + r * Wn + c];
            float e = __expf(-x[i]);
            p[i]  = __builtin_amdgcn_rcpf(1.0f + e);
            lp[i] = -__logf(1.0f + e);
        }

        float vmax = 0.0f, vmin = 2.0f;
        int cnt = 0;
        #pragma unroll
        for (int i = 0; i < 8; ++i) {
            const int rr = r - c_dy[i];
            const int cc = c - c_dx[i];
            const bool inb = (rr >= 0) & (rr < Hn) & (cc >= 0) & (cc < Wn);
            float pn = 0.0f, tn = 0.0f;
            if (inb) {
                float xn = cmb[(7 - i) * HWn + rr * Wn + cc];
                pn = __builtin_amdgcn_rcpf(1.0f + __expf(-xn));
                tn = (float)tgb[rr * Wn + cc];
            }
            const float v = p[i] * pn;           // vote i at this pixel
            vmax = fmaxf(vmax, v);
            vmin = fminf(vmin, v);
            const float ct = t_own * tn;          // conn_t in {0,1}
            cnt += (ct != 0.0f);
            // BCE term: ct*log(p) + (1-ct)*log(1-p), clamps never hit for |x|<88
            s_conn += (ct != 0.0f) ? lp[i] : (lp[i] - x[i]);
        }

        const bool edge = (cnt > 0) && (cnt < 8);
        if (edge) s_edge += fmaxf(log1pf(-vmin), -100.0f);

        s_bimap += (t_own != 0.0f) ? fmaxf(__logf(vmax), -100.0f)
                                   : fmaxf(log1pf(-vmax), -100.0f);
        s_inter += t_own * vmax;
        s_fp    += vmax;
        s_t     += t_own;
    }

    // wave64 tree reduce each partial, then combine across waves in LDS
    float vals[6] = {s_conn, s_bimap, s_edge, s_inter, s_fp, s_t};
    #pragma unroll
    for (int k = 0; k < 6; ++k) {
        float v = vals[k];
        #pragma unroll
        for (int off = 32; off > 0; off >>= 1) v += __shfl_down(v, off, 64);
        vals[k] = v;
    }
    __shared__ float bs[6];
    if (threadIdx.x < 6) bs[threadIdx.x] = 0.0f;
    __syncthreads();
    if ((threadIdx.x & 63) == 0) {
        #pragma unroll
        for (int k = 0; k < 6; ++k) atomicAdd(&bs[k], vals[k]);
    }
    __syncthreads();
    if (threadIdx.x < 6) atomicAdd(&ws[threadIdx.x], bs[threadIdx.x]);
}

__global__ void connect_loss_final(const float* __restrict__ ws,
                                   float* __restrict__ out)
{
    const float conn_l  = -ws[0] / (float)(8 * NPIX);
    const float bimap_l = -ws[1] / (float)NPIX;
    const float edge_l  = -ws[2] / (float)NPIX;
    const float dice_l  = 1.0f - (2.0f * ws[3] + 1.0f) / (ws[4] + ws[5] + 1.0f);
    out[0] = conn_l + bimap_l + edge_l + dice_l;
}

extern "C" void kernel_launch(void* const* d_in, const int* in_sizes, int n_in,
                              void* d_out, int out_size, void* d_ws, size_t ws_size,
                              hipStream_t stream) {
    const float* cm = (const float*)d_in[0];      // c_map (B,8,H,W) f32
    // d_in[1], d_in[2]: shift matrices (superdiagonal eye) — semantics hardcoded
    const int*   tg = (const int*)d_in[3];        // target (B,1,H,W) i32
    float* ws  = (float*)d_ws;
    float* out = (float*)d_out;

    hipMemsetAsync(ws, 0, 6 * sizeof(float), stream);
    connect_loss_main<<<2048, 256, 0, stream>>>(cm, tg, ws);
    connect_loss_final<<<1, 1, 0, stream>>>(ws, out);
}

// Round 2
// 50.536 us; speedup vs baseline: 1.2405x; 1.2405x over previous
//
#include <hip/hip_runtime.h>

constexpr int Bn  = 8;
constexpr int Hn  = 512;
constexpr int Wn  = 512;
constexpr int HWn = Hn * Wn;          // 262144
constexpr int NPIX = Bn * HWn;        // 2097152

typedef float f4  __attribute__((ext_vector_type(4)));               // 16B aligned
typedef int   i4  __attribute__((ext_vector_type(4)));
typedef float f4u __attribute__((ext_vector_type(4), aligned(4)));   // 4B-aligned vector load

// channel order: [down_right, down, down_left, right, left, up_right, up, up_left]
// conn_t[i][r,c] = t[r,c]*t[r-dy_i, c-dx_i];  vote[i][r,c] = p_i[r,c]*p_{7-i}[r-dy_i, c-dx_i]
// dy = {1,1,1,0,0,-1,-1,-1}, dx = {1,0,-1,1,-1,1,0,-1}

__global__ __launch_bounds__(256) void connect_loss_main(
    const float* __restrict__ cm,   // (B,8,H,W) f32
    const int*   __restrict__ tg,   // (B,1,H,W) i32
    float*       __restrict__ ws)   // 6 accumulators
{
    const int tid4 = blockIdx.x * 256 + threadIdx.x;   // one thread = 4 pixels
    const int pix  = tid4 * 4;
    const int c0 = pix & (Wn - 1);
    const int r  = (pix >> 9) & (Hn - 1);
    const int b  = pix >> 18;
    const float* cmb = cm + (size_t)b * 8 * HWn;
    const int*   tgb = tg + (size_t)b * HWn;

    // target row windows: rows r-1, r, r+1; columns c0-1 .. c0+4 (zero-padded)
    int w[3][6];
    #pragma unroll
    for (int dr = 0; dr < 3; ++dr) {
        const int row = r + dr - 1;
        const bool ok = (row >= 0) && (row < Hn);
        if (ok) {
            const int* trow = tgb + row * Wn;
            i4 a = *(const i4*)(trow + c0);            // 16B aligned
            w[dr][1] = a.x; w[dr][2] = a.y; w[dr][3] = a.z; w[dr][4] = a.w;
            w[dr][0] = (c0 > 0)      ? trow[c0 - 1] : 0;
            w[dr][5] = (c0 < Wn - 4) ? trow[c0 + 4] : 0;
        } else {
            #pragma unroll
            for (int j = 0; j < 6; ++j) w[dr][j] = 0;
        }
    }
    const int t_own[4] = {w[1][1], w[1][2], w[1][3], w[1][4]};

    f4 vmax = {0.f, 0.f, 0.f, 0.f};
    f4 vmin = {2.f, 2.f, 2.f, 2.f};
    int cnt[4] = {0, 0, 0, 0};
    float sconn = 0.f;

    #pragma unroll
    for (int i = 0; i < 8; ++i) {
        const int dy = (i < 3) ? 1 : ((i < 5) ? 0 : -1);
        const int dx = (i == 0 || i == 3 || i == 5) ? 1 : ((i == 1 || i == 6) ? 0 : -1);
        const int rr = r - dy;
        const int drw = 1 - dy;                        // window row index
        const bool rowok = (dy == 1) ? (r > 0) : ((dy == -1) ? (r < Hn - 1) : true);

        // own channel, aligned float4
        const f4 xo = *(const f4*)(cmb + (size_t)i * HWn + r * Wn + c0);
        // neighbor channel 7-i at (rr, c0-dx .. c0-dx+3), 4B-aligned vector load
        f4 xn = {0.f, 0.f, 0.f, 0.f};
        if (rowok) xn = *(const f4u*)(cmb + (size_t)(7 - i) * HWn + rr * Wn + (c0 - dx));

        f4 po, lpo, pn;
        #pragma unroll
        for (int j = 0; j < 4; ++j) {
            const float d = 1.0f + __expf(-xo[j]);
            po[j]  = __builtin_amdgcn_rcpf(d);
            lpo[j] = -__logf(d);
            pn[j]  = __builtin_amdgcn_rcpf(1.0f + __expf(-xn[j]));
        }
        if (!rowok) { pn[0] = pn[1] = pn[2] = pn[3] = 0.f; }
        if (dx == 1  && c0 == 0)      pn[0] = 0.f;     // column -1 pad
        if (dx == -1 && c0 == Wn - 4) pn[3] = 0.f;     // column 512 pad

        #pragma unroll
        for (int j = 0; j < 4; ++j) {
            const float v = po[j] * pn[j];
            vmax[j] = fmaxf(vmax[j], v);
            vmin[j] = fminf(vmin[j], v);
            const int tn = w[drw][j + 1 - dx];         // compile-time indices
            const bool ct = (t_own[j] != 0) & (tn != 0);
            cnt[j] += ct ? 1 : 0;
            // BCE term: ct ? log p : log(1-p);  log(1-p) = log p - x
            sconn += lpo[j] - (ct ? 0.0f : xo[j]);
        }
    }

    float sbimap = 0.f, sedge = 0.f, sinter = 0.f, sfp = 0.f, st = 0.f;
    #pragma unroll
    for (int j = 0; j < 4; ++j) {
        const float to = (float)t_own[j];
        if (cnt[j] > 0 && cnt[j] < 8)
            sedge += fmaxf(__logf(1.0f - vmin[j]), -100.0f);
        sbimap += (t_own[j] != 0) ? fmaxf(__logf(vmax[j]), -100.0f)
                                  : fmaxf(__logf(1.0f - vmax[j]), -100.0f);
        sinter += to * vmax[j];
        sfp    += vmax[j];
        st     += to;
    }

    // wave64 tree reduce, LDS combine, one global atomic set per block
    float vals[6] = {sconn, sbimap, sedge, sinter, sfp, st};
    #pragma unroll
    for (int k = 0; k < 6; ++k) {
        float v = vals[k];
        #pragma unroll
        for (int off = 32; off > 0; off >>= 1) v += __shfl_down(v, off, 64);
        vals[k] = v;
    }
    __shared__ float bs[6];
    if (threadIdx.x < 6) bs[threadIdx.x] = 0.0f;
    __syncthreads();
    if ((threadIdx.x & 63) == 0) {
        #pragma unroll
        for (int k = 0; k < 6; ++k) atomicAdd(&bs[k], vals[k]);
    }
    __syncthreads();
    if (threadIdx.x < 6) atomicAdd(&ws[threadIdx.x], bs[threadIdx.x]);
}

__global__ void connect_loss_final(const float* __restrict__ ws,
                                   float* __restrict__ out)
{
    const float conn_l  = -ws[0] / (float)(8 * NPIX);
    const float bimap_l = -ws[1] / (float)NPIX;
    const float edge_l  = -ws[2] / (float)NPIX;
    const float dice_l  = 1.0f - (2.0f * ws[3] + 1.0f) / (ws[4] + ws[5] + 1.0f);
    out[0] = conn_l + bimap_l + edge_l + dice_l;
}

extern "C" void kernel_launch(void* const* d_in, const int* in_sizes, int n_in,
                              void* d_out, int out_size, void* d_ws, size_t ws_size,
                              hipStream_t stream) {
    const float* cm = (const float*)d_in[0];      // c_map (B,8,H,W) f32
    const int*   tg = (const int*)d_in[3];        // target (B,1,H,W) i32
    float* ws  = (float*)d_ws;
    float* out = (float*)d_out;

    hipMemsetAsync(ws, 0, 6 * sizeof(float), stream);
    connect_loss_main<<<NPIX / 4 / 256, 256, 0, stream>>>(cm, tg, ws);
    connect_loss_final<<<1, 1, 0, stream>>>(ws, out);
}

// Round 3
// 50.361 us; speedup vs baseline: 1.2448x; 1.0035x over previous
//
#include <hip/hip_runtime.h>

constexpr int Bn  = 8;
constexpr int Hn  = 512;
constexpr int Wn  = 512;
constexpr int HWn = Hn * Wn;          // 262144
constexpr int NPIX = Bn * HWn;        // 2097152

typedef float f4  __attribute__((ext_vector_type(4)));               // 16B aligned
typedef int   i4  __attribute__((ext_vector_type(4)));
typedef float f4u __attribute__((ext_vector_type(4), aligned(4)));   // 4B-aligned vector load

// channel order: [down_right, down, down_left, right, left, up_right, up, up_left]
// conn_t[i][r,c] = t[r,c]*t[r-dy_i, c-dx_i];  vote[i][r,c] = p_i[r,c]*p_{7-i}[r-dy_i, c-dx_i]
#define DY(i) ((i) < 3 ? 1 : ((i) < 5 ? 0 : -1))
#define DX(i) (((i)==0 || (i)==3 || (i)==5) ? 1 : (((i)==1 || (i)==6) ? 0 : -1))

__global__ __launch_bounds__(256) void connect_loss_main(
    const float* __restrict__ cm,   // (B,8,H,W) f32
    const int*   __restrict__ tg,   // (B,1,H,W) i32
    float*       __restrict__ ws)   // 6 accumulators
{
    const int tid4 = blockIdx.x * 256 + threadIdx.x;   // one thread = 4 pixels
    const int pix  = tid4 * 4;
    const int c0 = pix & (Wn - 1);
    const int r  = (pix >> 9) & (Hn - 1);
    const int b  = pix >> 18;
    const float* cmb = cm + (size_t)b * 8 * HWn;
    const int*   tgb = tg + (size_t)b * HWn;
    const float* own = cmb + r * Wn + c0;

    // ---------- issue ALL global loads before any compute ----------
    f4 xo[8], xn[8];
    #pragma unroll
    for (int i = 0; i < 8; ++i)
        xo[i] = *(const f4*)(own + (size_t)i * HWn);

    const bool interior = (r > 0) & (r < Hn - 1);      // wave-uniform
    if (interior) {
        #pragma unroll
        for (int i = 0; i < 8; ++i)
            xn[i] = *(const f4u*)(cmb + (size_t)(7 - i) * HWn
                                  + (r - DY(i)) * Wn + (c0 - DX(i)));
    } else {
        #pragma unroll
        for (int i = 0; i < 8; ++i) {
            const bool rowok = (DY(i) == 1) ? (r > 0)
                             : ((DY(i) == -1) ? (r < Hn - 1) : true);
            if (rowok)
                xn[i] = *(const f4u*)(cmb + (size_t)(7 - i) * HWn
                                      + (r - DY(i)) * Wn + (c0 - DX(i)));
            else
                xn[i] = (f4){0.f, 0.f, 0.f, 0.f};
        }
    }

    // target row windows: rows r-1, r, r+1; cols c0-1 .. c0+4 (zero-padded)
    int w[3][6];
    #pragma unroll
    for (int dr = 0; dr < 3; ++dr) {
        const int row = r + dr - 1;
        const bool ok = (row >= 0) && (row < Hn);
        if (ok) {
            const int* trow = tgb + row * Wn;
            i4 a = *(const i4*)(trow + c0);
            w[dr][1] = a.x; w[dr][2] = a.y; w[dr][3] = a.z; w[dr][4] = a.w;
            w[dr][0] = (c0 > 0)      ? trow[c0 - 1] : 0;
            w[dr][5] = (c0 < Wn - 4) ? trow[c0 + 4] : 0;
        } else {
            #pragma unroll
            for (int j = 0; j < 6; ++j) w[dr][j] = 0;
        }
    }
    const int t_own[4] = {w[1][1], w[1][2], w[1][3], w[1][4]};

    // ---------- compute ----------
    f4 vmax = {0.f, 0.f, 0.f, 0.f};
    f4 vmin = {2.f, 2.f, 2.f, 2.f};
    int cnt[4] = {0, 0, 0, 0};
    float sconn = 0.f;

    #pragma unroll
    for (int i = 0; i < 8; ++i) {
        const int dx = DX(i);
        const int drw = 1 - DY(i);
        const bool rowok = (DY(i) == 1) ? (r > 0)
                         : ((DY(i) == -1) ? (r < Hn - 1) : true);
        f4 po, lpo, pn;
        #pragma unroll
        for (int j = 0; j < 4; ++j) {
            const float d = 1.0f + __expf(-xo[i][j]);
            po[j]  = __builtin_amdgcn_rcpf(d);
            lpo[j] = -__logf(d);
            pn[j]  = __builtin_amdgcn_rcpf(1.0f + __expf(-xn[i][j]));
        }
        if (!rowok) { pn[0] = pn[1] = pn[2] = pn[3] = 0.f; }
        if (dx == 1  && c0 == 0)      pn[0] = 0.f;     // column -1 pad
        if (dx == -1 && c0 == Wn - 4) pn[3] = 0.f;     // column 512 pad

        #pragma unroll
        for (int j = 0; j < 4; ++j) {
            const float v = po[j] * pn[j];
            vmax[j] = fmaxf(vmax[j], v);
            vmin[j] = fminf(vmin[j], v);
            const int tn = w[drw][j + 1 - dx];         // compile-time indices
            const bool ct = (t_own[j] != 0) & (tn != 0);
            cnt[j] += ct ? 1 : 0;
            sconn += lpo[j] - (ct ? 0.0f : xo[i][j]);  // ct?log p:log(1-p)
        }
    }

    float sbimap = 0.f, sedge = 0.f, sinter = 0.f, sfp = 0.f, st = 0.f;
    #pragma unroll
    for (int j = 0; j < 4; ++j) {
        const float to = (float)t_own[j];
        if (cnt[j] > 0 && cnt[j] < 8)
            sedge += fmaxf(__logf(1.0f - vmin[j]), -100.0f);
        sbimap += (t_own[j] != 0) ? fmaxf(__logf(vmax[j]), -100.0f)
                                  : fmaxf(__logf(1.0f - vmax[j]), -100.0f);
        sinter += to * vmax[j];
        sfp    += vmax[j];
        st     += to;
    }

    // wave64 tree reduce, LDS combine, one global atomic set per block
    float vals[6] = {sconn, sbimap, sedge, sinter, sfp, st};
    #pragma unroll
    for (int k = 0; k < 6; ++k) {
        float v = vals[k];
        #pragma unroll
        for (int off = 32; off > 0; off >>= 1) v += __shfl_down(v, off, 64);
        vals[k] = v;
    }
    __shared__ float bs[6];
    if (threadIdx.x < 6) bs[threadIdx.x] = 0.0f;
    __syncthreads();
    if ((threadIdx.x & 63) == 0) {
        #pragma unroll
        for (int k = 0; k < 6; ++k) atomicAdd(&bs[k], vals[k]);
    }
    __syncthreads();
    if (threadIdx.x < 6) atomicAdd(&ws[threadIdx.x], bs[threadIdx.x]);
}

__global__ void connect_loss_final(const float* __restrict__ ws,
                                   float* __restrict__ out)
{
    const float conn_l  = -ws[0] / (float)(8 * NPIX);
    const float bimap_l = -ws[1] / (float)NPIX;
    const float edge_l  = -ws[2] / (float)NPIX;
    const float dice_l  = 1.0f - (2.0f * ws[3] + 1.0f) / (ws[4] + ws[5] + 1.0f);
    out[0] = conn_l + bimap_l + edge_l + dice_l;
}

extern "C" void kernel_launch(void* const* d_in, const int* in_sizes, int n_in,
                              void* d_out, int out_size, void* d_ws, size_t ws_size,
                              hipStream_t stream) {
    const float* cm = (const float*)d_in[0];      // c_map (B,8,H,W) f32
    const int*   tg = (const int*)d_in[3];        // target (B,1,H,W) i32
    float* ws  = (float*)d_ws;
    float* out = (float*)d_out;

    hipMemsetAsync(ws, 0, 6 * sizeof(float), stream);
    connect_loss_main<<<NPIX / 4 / 256, 256, 0, stream>>>(cm, tg, ws);
    connect_loss_final<<<1, 1, 0, stream>>>(ws, out);
}

// Round 4
// 33.635 us; speedup vs baseline: 1.8639x; 1.4973x over previous
//
#include <hip/hip_runtime.h>

constexpr int Bn  = 8;
constexpr int Hn  = 512;
constexpr int Wn  = 512;
constexpr int HWn = Hn * Wn;          // 262144
constexpr int NPIX = Bn * HWn;        // 2097152
constexpr int NBLK = NPIX / 4 / 256;  // 2048 blocks, 4 px/thread

typedef float f4  __attribute__((ext_vector_type(4)));               // 16B aligned
typedef int   i4  __attribute__((ext_vector_type(4)));
typedef float f4u __attribute__((ext_vector_type(4), aligned(4)));   // 4B-aligned vector load

// channel order: [down_right, down, down_left, right, left, up_right, up, up_left]
// conn_t[i][r,c] = t[r,c]*t[r-dy_i, c-dx_i];  vote[i][r,c] = p_i[r,c]*p_{7-i}[r-dy_i, c-dx_i]
#define DY(i) ((i) < 3 ? 1 : ((i) < 5 ? 0 : -1))
#define DX(i) (((i)==0 || (i)==3 || (i)==5) ? 1 : (((i)==1 || (i)==6) ? 0 : -1))

__global__ __launch_bounds__(256) void connect_loss_main(
    const float* __restrict__ cm,   // (B,8,H,W) f32
    const int*   __restrict__ tg,   // (B,1,H,W) i32
    float*       __restrict__ ws)   // per-block partials: ws[k*NBLK + blk]
{
    const int tid4 = blockIdx.x * 256 + threadIdx.x;   // one thread = 4 pixels
    const int pix  = tid4 * 4;
    const int c0 = pix & (Wn - 1);
    const int r  = (pix >> 9) & (Hn - 1);
    const int b  = pix >> 18;
    const float* cmb = cm + (size_t)b * 8 * HWn;
    const int*   tgb = tg + (size_t)b * HWn;
    const float* own = cmb + r * Wn + c0;

    // ---------- issue ALL global loads before any compute ----------
    f4 xo[8], xn[8];
    #pragma unroll
    for (int i = 0; i < 8; ++i)
        xo[i] = *(const f4*)(own + (size_t)i * HWn);

    const bool interior = (r > 0) & (r < Hn - 1);      // wave-uniform
    if (interior) {
        #pragma unroll
        for (int i = 0; i < 8; ++i)
            xn[i] = *(const f4u*)(cmb + (size_t)(7 - i) * HWn
                                  + (r - DY(i)) * Wn + (c0 - DX(i)));
    } else {
        #pragma unroll
        for (int i = 0; i < 8; ++i) {
            const bool rowok = (DY(i) == 1) ? (r > 0)
                             : ((DY(i) == -1) ? (r < Hn - 1) : true);
            if (rowok)
                xn[i] = *(const f4u*)(cmb + (size_t)(7 - i) * HWn
                                      + (r - DY(i)) * Wn + (c0 - DX(i)));
            else
                xn[i] = (f4){0.f, 0.f, 0.f, 0.f};
        }
    }

    // target row windows: rows r-1, r, r+1; cols c0-1 .. c0+4 (zero-padded)
    int w[3][6];
    #pragma unroll
    for (int dr = 0; dr < 3; ++dr) {
        const int row = r + dr - 1;
        const bool ok = (row >= 0) && (row < Hn);
        if (ok) {
            const int* trow = tgb + row * Wn;
            i4 a = *(const i4*)(trow + c0);
            w[dr][1] = a.x; w[dr][2] = a.y; w[dr][3] = a.z; w[dr][4] = a.w;
            w[dr][0] = (c0 > 0)      ? trow[c0 - 1] : 0;
            w[dr][5] = (c0 < Wn - 4) ? trow[c0 + 4] : 0;
        } else {
            #pragma unroll
            for (int j = 0; j < 6; ++j) w[dr][j] = 0;
        }
    }
    // keep all loads above, compute below (MLP)
    __builtin_amdgcn_sched_barrier(0);

    const int t_own[4] = {w[1][1], w[1][2], w[1][3], w[1][4]};

    // ---------- compute ----------
    f4 vmax = {0.f, 0.f, 0.f, 0.f};
    f4 vmin = {2.f, 2.f, 2.f, 2.f};
    int cnt[4] = {0, 0, 0, 0};
    float sconn = 0.f;

    #pragma unroll
    for (int i = 0; i < 8; ++i) {
        const int dx = DX(i);
        const int drw = 1 - DY(i);
        const bool rowok = (DY(i) == 1) ? (r > 0)
                         : ((DY(i) == -1) ? (r < Hn - 1) : true);
        f4 po, lpo, pn;
        #pragma unroll
        for (int j = 0; j < 4; ++j) {
            const float d = 1.0f + __expf(-xo[i][j]);
            po[j]  = __builtin_amdgcn_rcpf(d);
            lpo[j] = -__logf(d);
            pn[j]  = __builtin_amdgcn_rcpf(1.0f + __expf(-xn[i][j]));
        }
        if (!rowok) { pn[0] = pn[1] = pn[2] = pn[3] = 0.f; }
        if (dx == 1  && c0 == 0)      pn[0] = 0.f;     // column -1 pad
        if (dx == -1 && c0 == Wn - 4) pn[3] = 0.f;     // column 512 pad

        #pragma unroll
        for (int j = 0; j < 4; ++j) {
            const float v = po[j] * pn[j];
            vmax[j] = fmaxf(vmax[j], v);
            vmin[j] = fminf(vmin[j], v);
            const int tn = w[drw][j + 1 - dx];         // compile-time indices
            const bool ct = (t_own[j] != 0) & (tn != 0);
            cnt[j] += ct ? 1 : 0;
            sconn += lpo[j] - (ct ? 0.0f : xo[i][j]);  // ct?log p:log(1-p)
        }
    }

    float sbimap = 0.f, sedge = 0.f, sinter = 0.f, sfp = 0.f, st = 0.f;
    #pragma unroll
    for (int j = 0; j < 4; ++j) {
        const float to = (float)t_own[j];
        if (cnt[j] > 0 && cnt[j] < 8)
            sedge += fmaxf(__logf(1.0f - vmin[j]), -100.0f);
        sbimap += (t_own[j] != 0) ? fmaxf(__logf(vmax[j]), -100.0f)
                                  : fmaxf(__logf(1.0f - vmax[j]), -100.0f);
        sinter += to * vmax[j];
        sfp    += vmax[j];
        st     += to;
    }

    // wave64 tree reduce, LDS combine, ONE plain store set per block (no
    // global atomics — same-line atomic contention was the ~50 µs floor)
    float vals[6] = {sconn, sbimap, sedge, sinter, sfp, st};
    #pragma unroll
    for (int k = 0; k < 6; ++k) {
        float v = vals[k];
        #pragma unroll
        for (int off = 32; off > 0; off >>= 1) v += __shfl_down(v, off, 64);
        vals[k] = v;
    }
    __shared__ float bs[6];
    if (threadIdx.x < 6) bs[threadIdx.x] = 0.0f;
    __syncthreads();
    if ((threadIdx.x & 63) == 0) {
        #pragma unroll
        for (int k = 0; k < 6; ++k) atomicAdd(&bs[k], vals[k]);
    }
    __syncthreads();
    if (threadIdx.x < 6)
        ws[threadIdx.x * NBLK + blockIdx.x] = bs[threadIdx.x];
}

// single-block reduce of 6 x NBLK partials + final loss
__global__ __launch_bounds__(256) void connect_loss_reduce(
    const float* __restrict__ ws, float* __restrict__ out)
{
    float acc[6];
    #pragma unroll
    for (int k = 0; k < 6; ++k) {
        const f4* p = (const f4*)(ws + k * NBLK + threadIdx.x * 8);
        const f4 a = p[0], b2 = p[1];                   // 256*8 = 2048 = NBLK
        acc[k] = (a.x + a.y) + (a.z + a.w) + (b2.x + b2.y) + (b2.z + b2.w);
    }
    #pragma unroll
    for (int k = 0; k < 6; ++k) {
        float v = acc[k];
        #pragma unroll
        for (int off = 32; off > 0; off >>= 1) v += __shfl_down(v, off, 64);
        acc[k] = v;
    }
    __shared__ float bs[6];
    if (threadIdx.x < 6) bs[threadIdx.x] = 0.0f;
    __syncthreads();
    if ((threadIdx.x & 63) == 0) {
        #pragma unroll
        for (int k = 0; k < 6; ++k) atomicAdd(&bs[k], acc[k]);
    }
    __syncthreads();
    if (threadIdx.x == 0) {
        const float conn_l  = -bs[0] / (float)(8 * NPIX);
        const float bimap_l = -bs[1] / (float)NPIX;
        const float edge_l  = -bs[2] / (float)NPIX;
        const float dice_l  = 1.0f - (2.0f * bs[3] + 1.0f) / (bs[4] + bs[5] + 1.0f);
        out[0] = conn_l + bimap_l + edge_l + dice_l;
    }
}

extern "C" void kernel_launch(void* const* d_in, const int* in_sizes, int n_in,
                              void* d_out, int out_size, void* d_ws, size_t ws_size,
                              hipStream_t stream) {
    const float* cm = (const float*)d_in[0];      // c_map (B,8,H,W) f32
    const int*   tg = (const int*)d_in[3];        // target (B,1,H,W) i32
    float* ws  = (float*)d_ws;                    // 6*NBLK floats (48 KB)
    float* out = (float*)d_out;

    connect_loss_main<<<NBLK, 256, 0, stream>>>(cm, tg, ws);
    connect_loss_reduce<<<1, 256, 0, stream>>>(ws, out);
}

// Round 5
// 33.427 us; speedup vs baseline: 1.8755x; 1.0062x over previous
//
#include <hip/hip_runtime.h>

constexpr int Bn  = 8;
constexpr int Hn  = 512;
constexpr int Wn  = 512;
constexpr int HWn = Hn * Wn;          // 262144
constexpr int NPIX = Bn * HWn;        // 2097152
constexpr int NBLK = 2048;            // 4 waves/block, wave = half row (256 px)

typedef float f4 __attribute__((ext_vector_type(4)));
typedef int   i4 __attribute__((ext_vector_type(4)));

// channel order: [down_right, down, down_left, right, left, up_right, up, up_left]
// conn_t[i][r,c] = t[r,c]*t[r-dy_i,c-dx_i]; vote[i][r,c] = p_i[r,c]*p_{7-i}[r-dy_i,c-dx_i]
// dy = {1,1,1,0,0,-1,-1,-1}, dx = {1,0,-1,1,-1,1,0,-1}

__device__ __forceinline__ float sigm(float x) {
    return __builtin_amdgcn_rcpf(1.0f + __expf(-x));
}
// value at col c-1 for a wave-contiguous f4 row segment
__device__ __forceinline__ f4 shrf(f4 v, float edge, int lane) {
    float u = __shfl_up(v.w, 1, 64);
    if (lane == 0) u = edge;
    return (f4){u, v.x, v.y, v.z};
}
// value at col c+1
__device__ __forceinline__ f4 shlf(f4 v, float edge, int lane) {
    float d = __shfl_down(v.x, 1, 64);
    if (lane == 63) d = edge;
    return (f4){v.y, v.z, v.w, d};
}
__device__ __forceinline__ i4 shri(i4 v, int edge, int lane) {
    int u = __shfl_up(v.w, 1, 64);
    if (lane == 0) u = edge;
    return (i4){u, v.x, v.y, v.z};
}
__device__ __forceinline__ i4 shli(i4 v, int edge, int lane) {
    int d = __shfl_down(v.x, 1, 64);
    if (lane == 63) d = edge;
    return (i4){v.y, v.z, v.w, d};
}

__global__ __launch_bounds__(256) void connect_loss_main(
    const float* __restrict__ cm,   // (B,8,H,W) f32
    const int*   __restrict__ tg,   // (B,1,H,W) i32
    float*       __restrict__ ws)   // per-block partials ws[k*NBLK + blk]
{
    const int lane   = threadIdx.x & 63;
    const int gw     = blockIdx.x * 4 + (threadIdx.x >> 6);
    const int half   = gw & 1;              // which half-row
    const int rowIdx = gw >> 1;             // 0..4095
    const int r = rowIdx & (Hn - 1);
    const int b = rowIdx >> 9;
    const int w0 = half * 256;
    const int c0 = w0 + lane * 4;

    const float* cmb  = cm + (size_t)b * 8 * HWn;
    const int*   tgb  = tg + (size_t)b * HWn;
    const float* rowp = cmb + (size_t)r * Wn;

    const bool hasUp = (r > 0), hasDn = (r < Hn - 1);   // wave-uniform
    const bool hasL  = (w0 > 0), hasR = (w0 + 256 < Wn);
    const int  cL = w0 - 1, cR = w0 + 256;

    // ---------- aligned vector loads only ----------
    f4 xo[8];
    #pragma unroll
    for (int ch = 0; ch < 8; ++ch)
        xo[ch] = *(const f4*)(rowp + (size_t)ch * HWn + c0);

    f4 xm5, xm6, xm7, xp0, xp1, xp2;
    if (hasUp) {
        const float* rm = cmb + (size_t)(r - 1) * Wn;
        xm5 = *(const f4*)(rm + (size_t)5 * HWn + c0);
        xm6 = *(const f4*)(rm + (size_t)6 * HWn + c0);
        xm7 = *(const f4*)(rm + (size_t)7 * HWn + c0);
    }
    if (hasDn) {
        const float* rp = cmb + (size_t)(r + 1) * Wn;
        xp0 = *(const f4*)(rp + (size_t)0 * HWn + c0);
        xp1 = *(const f4*)(rp + (size_t)1 * HWn + c0);
        xp2 = *(const f4*)(rp + (size_t)2 * HWn + c0);
    }

    i4 tt = *(const i4*)(tgb + (size_t)r * Wn + c0);
    i4 tm = hasUp ? *(const i4*)(tgb + (size_t)(r - 1) * Wn + c0) : (i4){0, 0, 0, 0};
    i4 tp = hasDn ? *(const i4*)(tgb + (size_t)(r + 1) * Wn + c0) : (i4){0, 0, 0, 0};

    // wave-uniform edge patches (broadcast loads)
    // shr (c-1) patches at col cL: ch7@r-1, ch4@r, ch2@r+1 ; shl (c+1) at cR: ch5@r-1, ch3@r, ch0@r+1
    float pLm = 0.f, pLt = 0.f, pLp = 0.f, pRm = 0.f, pRt = 0.f, pRp = 0.f;
    int   tLm = 0, tLt = 0, tLp = 0, tRm = 0, tRt = 0, tRp = 0;
    if (hasL) {
        pLt = sigm(rowp[(size_t)4 * HWn + cL]);
        tLt = tgb[(size_t)r * Wn + cL];
        if (hasUp) { pLm = sigm(cmb[(size_t)7 * HWn + (size_t)(r - 1) * Wn + cL]);
                     tLm = tgb[(size_t)(r - 1) * Wn + cL]; }
        if (hasDn) { pLp = sigm(cmb[(size_t)2 * HWn + (size_t)(r + 1) * Wn + cL]);
                     tLp = tgb[(size_t)(r + 1) * Wn + cL]; }
    }
    if (hasR) {
        pRt = sigm(rowp[(size_t)3 * HWn + cR]);
        tRt = tgb[(size_t)r * Wn + cR];
        if (hasUp) { pRm = sigm(cmb[(size_t)5 * HWn + (size_t)(r - 1) * Wn + cR]);
                     tRm = tgb[(size_t)(r - 1) * Wn + cR]; }
        if (hasDn) { pRp = sigm(cmb[(size_t)0 * HWn + (size_t)(r + 1) * Wn + cR]);
                     tRp = tgb[(size_t)(r + 1) * Wn + cR]; }
    }

    // ---------- sigmoids ----------
    f4 po[8], lpo[8];
    #pragma unroll
    for (int ch = 0; ch < 8; ++ch) {
        #pragma unroll
        for (int j = 0; j < 4; ++j) {
            const float d = 1.0f + __expf(-xo[ch][j]);
            po[ch][j]  = __builtin_amdgcn_rcpf(d);
            lpo[ch][j] = -__logf(d);
        }
    }
    f4 pm5, pm6, pm7, pp0, pp1, pp2;
    if (hasUp) {
        #pragma unroll
        for (int j = 0; j < 4; ++j) {
            pm5[j] = sigm(xm5[j]); pm6[j] = sigm(xm6[j]); pm7[j] = sigm(xm7[j]);
        }
    } else pm5 = pm6 = pm7 = (f4){0.f, 0.f, 0.f, 0.f};
    if (hasDn) {
        #pragma unroll
        for (int j = 0; j < 4; ++j) {
            pp0[j] = sigm(xp0[j]); pp1[j] = sigm(xp1[j]); pp2[j] = sigm(xp2[j]);
        }
    } else pp0 = pp1 = pp2 = (f4){0.f, 0.f, 0.f, 0.f};

    // ---------- shifted neighbor vectors (register shuffles) ----------
    f4 pn[8];
    pn[0] = shrf(pm7, pLm, lane);       // ch7 @ (r-1, c-1)
    pn[1] = pm6;                        // ch6 @ (r-1, c)
    pn[2] = shlf(pm5, pRm, lane);       // ch5 @ (r-1, c+1)
    pn[3] = shrf(po[4], pLt, lane);     // ch4 @ (r,   c-1)
    pn[4] = shlf(po[3], pRt, lane);     // ch3 @ (r,   c+1)
    pn[5] = shrf(pp2, pLp, lane);       // ch2 @ (r+1, c-1)
    pn[6] = pp1;                        // ch1 @ (r+1, c)
    pn[7] = shlf(pp0, pRp, lane);       // ch0 @ (r+1, c+1)

    i4 tn[8];
    tn[0] = shri(tm, tLm, lane);
    tn[1] = tm;
    tn[2] = shli(tm, tRm, lane);
    tn[3] = shri(tt, tLt, lane);
    tn[4] = shli(tt, tRt, lane);
    tn[5] = shri(tp, tLp, lane);
    tn[6] = tp;
    tn[7] = shli(tp, tRp, lane);

    // ---------- accumulate ----------
    f4 vmax = {0.f, 0.f, 0.f, 0.f};
    f4 vmin = {2.f, 2.f, 2.f, 2.f};
    int cnt[4] = {0, 0, 0, 0};
    float sconn = 0.f;

    #pragma unroll
    for (int i = 0; i < 8; ++i) {
        #pragma unroll
        for (int j = 0; j < 4; ++j) {
            const float v = po[i][j] * pn[i][j];
            vmax[j] = fmaxf(vmax[j], v);
            vmin[j] = fminf(vmin[j], v);
            const bool ct = (tt[j] != 0) & (tn[i][j] != 0);
            cnt[j] += ct ? 1 : 0;
            sconn += lpo[i][j] - (ct ? 0.0f : xo[i][j]);   // ct?log p:log(1-p)
        }
    }

    float sbimap = 0.f, sedge = 0.f, sinter = 0.f, sfp = 0.f, st = 0.f;
    #pragma unroll
    for (int j = 0; j < 4; ++j) {
        const float to = (float)tt[j];
        if (cnt[j] > 0 && cnt[j] < 8)
            sedge += fmaxf(__logf(1.0f - vmin[j]), -100.0f);
        sbimap += (tt[j] != 0) ? fmaxf(__logf(vmax[j]), -100.0f)
                               : fmaxf(__logf(1.0f - vmax[j]), -100.0f);
        sinter += to * vmax[j];
        sfp    += vmax[j];
        st     += to;
    }

    // wave64 tree reduce, LDS combine, plain per-block stores (no global atomics)
    float vals[6] = {sconn, sbimap, sedge, sinter, sfp, st};
    #pragma unroll
    for (int k = 0; k < 6; ++k) {
        float v = vals[k];
        #pragma unroll
        for (int off = 32; off > 0; off >>= 1) v += __shfl_down(v, off, 64);
        vals[k] = v;
    }
    __shared__ float bs[6];
    if (threadIdx.x < 6) bs[threadIdx.x] = 0.0f;
    __syncthreads();
    if ((threadIdx.x & 63) == 0) {
        #pragma unroll
        for (int k = 0; k < 6; ++k) atomicAdd(&bs[k], vals[k]);
    }
    __syncthreads();
    if (threadIdx.x < 6)
        ws[threadIdx.x * NBLK + blockIdx.x] = bs[threadIdx.x];
}

// single-block reduce of 6 x NBLK partials + final loss
__global__ __launch_bounds__(256) void connect_loss_reduce(
    const float* __restrict__ ws, float* __restrict__ out)
{
    float acc[6];
    #pragma unroll
    for (int k = 0; k < 6; ++k) {
        const f4* p = (const f4*)(ws + k * NBLK + threadIdx.x * 8);
        const f4 a = p[0], b2 = p[1];                   // 256*8 = 2048 = NBLK
        acc[k] = (a.x + a.y) + (a.z + a.w) + (b2.x + b2.y) + (b2.z + b2.w);
    }
    #pragma unroll
    for (int k = 0; k < 6; ++k) {
        float v = acc[k];
        #pragma unroll
        for (int off = 32; off > 0; off >>= 1) v += __shfl_down(v, off, 64);
        acc[k] = v;
    }
    __shared__ float bs[6];
    if (threadIdx.x < 6) bs[threadIdx.x] = 0.0f;
    __syncthreads();
    if ((threadIdx.x & 63) == 0) {
        #pragma unroll
        for (int k = 0; k < 6; ++k) atomicAdd(&bs[k], acc[k]);
    }
    __syncthreads();
    if (threadIdx.x == 0) {
        const float conn_l  = -bs[0] / (float)(8 * NPIX);
        const float bimap_l = -bs[1] / (float)NPIX;
        const float edge_l  = -bs[2] / (float)NPIX;
        const float dice_l  = 1.0f - (2.0f * bs[3] + 1.0f) / (bs[4] + bs[5] + 1.0f);
        out[0] = conn_l + bimap_l + edge_l + dice_l;
    }
}

extern "C" void kernel_launch(void* const* d_in, const int* in_sizes, int n_in,
                              void* d_out, int out_size, void* d_ws, size_t ws_size,
                              hipStream_t stream) {
    const float* cm = (const float*)d_in[0];      // c_map (B,8,H,W) f32
    const int*   tg = (const int*)d_in[3];        // target (B,1,H,W) i32
    float* ws  = (float*)d_ws;                    // 6*NBLK floats (48 KB)
    float* out = (float*)d_out;

    connect_loss_main<<<NBLK, 256, 0, stream>>>(cm, tg, ws);
    connect_loss_reduce<<<1, 256, 0, stream>>>(ws, out);
}